// Round 2
// baseline (199.753 us; speedup 1.0000x reference)
//
#include <hip/hip_runtime.h>
#include <cstdint>
#include <cstddef>

// Problem dims
#define BB 8
#define HH 512
#define PP 512
#define LL 2048

typedef __attribute__((ext_vector_type(8))) __bf16 bf16x8;
typedef __attribute__((ext_vector_type(4))) float f32x4;

__device__ __forceinline__ uint16_t f2bf(float f) {
  uint32_t u = __builtin_bit_cast(uint32_t, f);
  u += 0x7FFFu + ((u >> 16) & 1u);   // RNE
  return (uint16_t)(u >> 16);
}

__device__ __forceinline__ void async_copy16(const void* gptr, void* ldsptr) {
  __builtin_amdgcn_global_load_lds(
      (const __attribute__((address_space(1))) unsigned int*)gptr,
      (__attribute__((address_space(3))) unsigned int*)ldsptr,
      16, 0, 0);
}

// ---------------------------------------------------------------------------
// prep: A1 (1024x512 bf16) = [B_re; B_im], A2 (512x1024 bf16) = [C_re, -C_im],
//       Dd (512 f32) = diag(D)
// ---------------------------------------------------------------------------
__global__ __launch_bounds__(256) void prep_mats(
    const float* __restrict__ Bbar, const float* __restrict__ Cri,
    const float* __restrict__ Dm,
    uint16_t* __restrict__ A1, uint16_t* __restrict__ A2,
    float* __restrict__ Dd) {
  int idx = blockIdx.x * 256 + threadIdx.x;   // 0 .. 512*512-1
  int p = idx >> 9, h = idx & 511;
  A1[(size_t)p * 512 + h]          = f2bf(Bbar[((size_t)p * 512 + h) * 2 + 0]);
  A1[(size_t)(512 + p) * 512 + h]  = f2bf(Bbar[((size_t)p * 512 + h) * 2 + 1]);
  int h2 = idx >> 9, p2 = idx & 511;
  A2[(size_t)h2 * 1024 + p2]        = f2bf( Cri[((size_t)h2 * 512 + p2) * 2 + 0]);
  A2[(size_t)h2 * 1024 + 512 + p2]  = f2bf(-Cri[((size_t)h2 * 512 + p2) * 2 + 1]);
  if (idx < 512) Dd[idx] = Dm[(size_t)idx * 512 + idx];
}

// ---------------------------------------------------------------------------
// scan: in-place on Bu (B, 1024, 2048) bf16 (rows p = re, rows 512+p = im)
// one wave per (b,p) chain; lane-local serial scan of 32 + Kogge-Stone combine
// ---------------------------------------------------------------------------
__global__ __launch_bounds__(256) void scan_kernel(
    const float* __restrict__ Lam, uint16_t* __restrict__ Bu) {
  const int gt = blockIdx.x * 256 + threadIdx.x;
  const int wave = gt >> 6, lane = gt & 63;
  const int b = wave >> 9, p = wave & 511;
  const float lr = Lam[p * 2 + 0], li = Lam[p * 2 + 1];
  float ar = lr, ai = li;
#pragma unroll
  for (int s = 0; s < 5; ++s) { float nr = ar * ar - ai * ai, ni = 2.f * ar * ai; ar = nr; ai = ni; }

  uint16_t* rowre = Bu + ((size_t)(b * 1024 + p)) * 2048 + lane * 32;
  uint16_t* rowim = Bu + ((size_t)(b * 1024 + 512 + p)) * 2048 + lane * 32;
  uint4 vr[4], vi[4];
#pragma unroll
  for (int q = 0; q < 4; ++q) { vr[q] = ((const uint4*)rowre)[q]; vi[q] = ((const uint4*)rowim)[q]; }

  float xr[32], xi[32];
  float sr = 0.f, si = 0.f;
#pragma unroll
  for (int q = 0; q < 4; ++q) {
    uint32_t wr[4] = {vr[q].x, vr[q].y, vr[q].z, vr[q].w};
    uint32_t wi[4] = {vi[q].x, vi[q].y, vi[q].z, vi[q].w};
#pragma unroll
    for (int d = 0; d < 4; ++d) {
      float br0 = __builtin_bit_cast(float, wr[d] << 16);
      float bi0 = __builtin_bit_cast(float, wi[d] << 16);
      float br1 = __builtin_bit_cast(float, wr[d] & 0xFFFF0000u);
      float bi1 = __builtin_bit_cast(float, wi[d] & 0xFFFF0000u);
      int j = q * 8 + d * 2;
      float nr = lr * sr - li * si + br0, ni = lr * si + li * sr + bi0;
      sr = nr; si = ni; xr[j] = sr; xi[j] = si;
      nr = lr * sr - li * si + br1; ni = lr * si + li * sr + bi1;
      sr = nr; si = ni; xr[j + 1] = sr; xi[j + 1] = si;
    }
  }
  float Ar = ar, Ai = ai, Sr = sr, Si = si;
#pragma unroll
  for (int off = 1; off < 64; off <<= 1) {
    float pAr = __shfl_up(Ar, off), pAi = __shfl_up(Ai, off);
    float pSr = __shfl_up(Sr, off), pSi = __shfl_up(Si, off);
    if (lane >= off) {
      float tSr = Ar * pSr - Ai * pSi + Sr;
      float tSi = Ar * pSi + Ai * pSr + Si;
      float tAr = Ar * pAr - Ai * pAi;
      float tAi = Ar * pAi + Ai * pAr;
      Sr = tSr; Si = tSi; Ar = tAr; Ai = tAi;
    }
  }
  float Cr = __shfl_up(Sr, 1), Ci = __shfl_up(Si, 1);
  if (lane == 0) { Cr = 0.f; Ci = 0.f; }
  float fr_ = lr * Cr - li * Ci, fi_ = lr * Ci + li * Cr;
#pragma unroll
  for (int j = 0; j < 32; ++j) {
    xr[j] += fr_; xi[j] += fi_;
    float nfr = fr_ * lr - fi_ * li, nfi = fr_ * li + fi_ * lr;
    fr_ = nfr; fi_ = nfi;
  }
#pragma unroll
  for (int q = 0; q < 4; ++q) {
    uint32_t wr[4], wi[4];
#pragma unroll
    for (int d = 0; d < 4; ++d) {
      int j = q * 8 + d * 2;
      wr[d] = (uint32_t)f2bf(xr[j]) | ((uint32_t)f2bf(xr[j + 1]) << 16);
      wi[d] = (uint32_t)f2bf(xi[j]) | ((uint32_t)f2bf(xi[j + 1]) << 16);
    }
    ((uint4*)rowre)[q] = make_uint4(wr[0], wr[1], wr[2], wr[3]);
    ((uint4*)rowim)[q] = make_uint4(wi[0], wi[1], wi[2], wi[3]);
  }
}

// ---------------------------------------------------------------------------
// GEMM1 fused: Bu[b,m,l] = sum_h A1[m,h] * u[b,h,l]. M=1024, N=2048, K=512.
// B-operand (u, f32, l-contiguous) transposed during staging:
//   thread (kp=t>>4, lg=t&15) loads 2 k-rows x 8 l f32, converts to bf16,
//   packs k-pairs, ds_write_b32 into Blds[l][k] (pitch 40, 16B-chunk swizzled).
// A staged via async copy with source-side chunk swizzle (kills 4-way reads).
// ---------------------------------------------------------------------------
__global__ __launch_bounds__(256) void gemm1_fused(
    const uint16_t* __restrict__ A, const float* __restrict__ U,
    uint16_t* __restrict__ Bu) {
  __shared__ __align__(16) uint16_t Alds[128 * 32];
  __shared__ __align__(16) uint16_t Blds[128 * 40];
  const int t = threadIdx.x, lane = t & 63, w = t >> 6;
  const int m0 = blockIdx.y * 128, n0 = blockIdx.x * 128, b = blockIdx.z;

  // A staging: r = t>>2 (row), c = t&3 (LDS 16B slot); fetch global chunk c^s(r)
  const int ra = t >> 2;
  const int qa = ((t & 3) ^ ((ra >> 1) & 3)) * 8;
  const uint16_t* gA0 = A + (size_t)(m0 + ra) * 512 + qa;
  const uint16_t* gA1 = A + (size_t)(m0 + 64 + ra) * 512 + qa;

  // B staging: kp = k-pair index (0..15), lg = 8-l group (0..15)
  const int kp = t >> 4, lg = t & 15;
  const float* gB = U + ((size_t)b * 512 + 2 * kp) * 2048 + n0 + lg * 8;
  const int bcol = ((kp >> 2) ^ (lg & 3)) * 8 + (kp & 3) * 2;  // element col in Blds row

  f32x4 acc[4][4];
#pragma unroll
  for (int i = 0; i < 4; ++i)
#pragma unroll
    for (int j = 0; j < 4; ++j) acc[i][j] = (f32x4){0.f, 0.f, 0.f, 0.f};

  const int wm = (w >> 1) * 64, wn = (w & 1) * 64;
  const int fr = lane & 15, fq = lane >> 4;
  const int aswz = (fq ^ ((fr >> 1) & 3)) * 8;   // A frag chunk slot (elements)

  for (int kb = 0; kb < 512; kb += 32) {
    async_copy16(gA0 + kb, Alds + (size_t)t * 8);
    async_copy16(gA1 + kb, Alds + 2048 + (size_t)t * 8);
    const float* s0 = gB + (size_t)kb * 2048;
    float4 a0 = *(const float4*)(s0);
    float4 a1 = *(const float4*)(s0 + 4);
    float4 b0 = *(const float4*)(s0 + 2048);
    float4 b1 = *(const float4*)(s0 + 2052);
    float r0[8] = {a0.x, a0.y, a0.z, a0.w, a1.x, a1.y, a1.z, a1.w};
    float r1[8] = {b0.x, b0.y, b0.z, b0.w, b1.x, b1.y, b1.z, b1.w};
#pragma unroll
    for (int j = 0; j < 8; ++j) {
      uint32_t wv = (uint32_t)f2bf(r0[j]) | ((uint32_t)f2bf(r1[j]) << 16);
      *(uint32_t*)&Blds[(lg * 8 + j) * 40 + bcol] = wv;
    }
    __syncthreads();
    bf16x8 af[4], bfr[4];
#pragma unroll
    for (int i = 0; i < 4; ++i)
      af[i] = *(const bf16x8*)&Alds[(wm + i * 16 + fr) * 32 + aswz];
#pragma unroll
    for (int j = 0; j < 4; ++j) {
      int n = wn + j * 16 + fr;
      bfr[j] = *(const bf16x8*)&Blds[n * 40 + ((fq ^ ((n >> 3) & 3)) * 8)];
    }
#pragma unroll
    for (int i = 0; i < 4; ++i)
#pragma unroll
      for (int j = 0; j < 4; ++j)
        acc[i][j] = __builtin_amdgcn_mfma_f32_16x16x32_bf16(af[i], bfr[j], acc[i][j], 0, 0, 0);
    __syncthreads();
  }

  uint16_t* O = Bu + ((size_t)b * 1024 + m0) * 2048 + n0;
#pragma unroll
  for (int i = 0; i < 4; ++i)
#pragma unroll
    for (int j = 0; j < 4; ++j)
#pragma unroll
      for (int r = 0; r < 4; ++r) {
        int mm = wm + i * 16 + fq * 4 + r;
        int nn = wn + j * 16 + fr;
        O[(size_t)mm * 2048 + nn] = f2bf(acc[i][j][r]);
      }
}

// ---------------------------------------------------------------------------
// GEMM2 fused: out[b,h,l] = gelu( sum_k A2[h,k]*x[b,k,l] + Dd[h]*u[b,h,l] )
// M=512, N=2048, K=1024. B-operand (x = scanned Bu, bf16, l-contiguous)
// transposed during staging (same swizzled Blds scheme, bf16 source).
// ---------------------------------------------------------------------------
__global__ __launch_bounds__(256) void gemm2_fused(
    const uint16_t* __restrict__ A, const uint16_t* __restrict__ X,
    float* __restrict__ Out, const float* __restrict__ Dd,
    const float* __restrict__ Uu) {
  __shared__ __align__(16) uint16_t Alds[128 * 32];
  __shared__ __align__(16) uint16_t Blds[128 * 40];
  const int t = threadIdx.x, lane = t & 63, w = t >> 6;
  const int m0 = blockIdx.y * 128, n0 = blockIdx.x * 128, b = blockIdx.z;

  const int ra = t >> 2;
  const int qa = ((t & 3) ^ ((ra >> 1) & 3)) * 8;
  const uint16_t* gA0 = A + (size_t)(m0 + ra) * 1024 + qa;
  const uint16_t* gA1 = A + (size_t)(m0 + 64 + ra) * 1024 + qa;

  const int kp = t >> 4, lg = t & 15;
  const uint16_t* gB = X + ((size_t)b * 1024 + 2 * kp) * 2048 + n0 + lg * 8;
  const int bcol = ((kp >> 2) ^ (lg & 3)) * 8 + (kp & 3) * 2;

  f32x4 acc[4][4];
#pragma unroll
  for (int i = 0; i < 4; ++i)
#pragma unroll
    for (int j = 0; j < 4; ++j) acc[i][j] = (f32x4){0.f, 0.f, 0.f, 0.f};

  const int wm = (w >> 1) * 64, wn = (w & 1) * 64;
  const int fr = lane & 15, fq = lane >> 4;
  const int aswz = (fq ^ ((fr >> 1) & 3)) * 8;

  for (int kb = 0; kb < 1024; kb += 32) {
    async_copy16(gA0 + kb, Alds + (size_t)t * 8);
    async_copy16(gA1 + kb, Alds + 2048 + (size_t)t * 8);
    const uint16_t* s0 = gB + (size_t)kb * 2048;
    uint4 q0 = *(const uint4*)(s0);          // row 2kp,   8 bf16
    uint4 q1 = *(const uint4*)(s0 + 2048);   // row 2kp+1, 8 bf16
    uint32_t u0[4] = {q0.x, q0.y, q0.z, q0.w};
    uint32_t u1[4] = {q1.x, q1.y, q1.z, q1.w};
#pragma unroll
    for (int d = 0; d < 4; ++d) {
      uint32_t lo = (u0[d] & 0xFFFFu) | (u1[d] << 16);          // l = 2d
      uint32_t hi = (u0[d] >> 16) | (u1[d] & 0xFFFF0000u);      // l = 2d+1
      *(uint32_t*)&Blds[(lg * 8 + 2 * d + 0) * 40 + bcol] = lo;
      *(uint32_t*)&Blds[(lg * 8 + 2 * d + 1) * 40 + bcol] = hi;
    }
    __syncthreads();
    bf16x8 af[4], bfr[4];
#pragma unroll
    for (int i = 0; i < 4; ++i)
      af[i] = *(const bf16x8*)&Alds[(wm + i * 16 + fr) * 32 + aswz];
#pragma unroll
    for (int j = 0; j < 4; ++j) {
      int n = wn + j * 16 + fr;
      bfr[j] = *(const bf16x8*)&Blds[n * 40 + ((fq ^ ((n >> 3) & 3)) * 8)];
    }
#pragma unroll
    for (int i = 0; i < 4; ++i)
#pragma unroll
      for (int j = 0; j < 4; ++j)
        acc[i][j] = __builtin_amdgcn_mfma_f32_16x16x32_bf16(af[i], bfr[j], acc[i][j], 0, 0, 0);
    __syncthreads();
  }

  const size_t base = ((size_t)b * 512 + m0) * 2048 + n0;
  float* O = Out + base;
  const float* Ub = Uu + base;
#pragma unroll
  for (int i = 0; i < 4; ++i)
#pragma unroll
    for (int r = 0; r < 4; ++r) {
      int mm = wm + i * 16 + fq * 4 + r;
      float dv = Dd[m0 + mm];
#pragma unroll
      for (int j = 0; j < 4; ++j) {
        int nn = wn + j * 16 + fr;
        float xv = acc[i][j][r] + dv * Ub[(size_t)mm * 2048 + nn];
        O[(size_t)mm * 2048 + nn] = 0.5f * xv * (1.f + erff(xv * 0.70710678118654752f));
      }
    }
}

// ---------------------------------------------------------------------------
extern "C" void kernel_launch(void* const* d_in, const int* in_sizes, int n_in,
                              void* d_out, int out_size, void* d_ws, size_t ws_size,
                              hipStream_t stream) {
  const float* u    = (const float*)d_in[0];   // (8,512,2048)
  const float* Lam  = (const float*)d_in[1];   // (512,2)
  const float* Bbar = (const float*)d_in[2];   // (512,512,2)
  const float* Cri  = (const float*)d_in[3];   // (512,512,2)
  const float* Dm   = (const float*)d_in[4];   // (512,512)
  float* out = (float*)d_out;

  char* ws = (char*)d_ws;
  uint16_t* Bu = (uint16_t*)(ws);                    // (8,1024,2048) bf16, 33.55 MB
  uint16_t* A1 = (uint16_t*)(ws + 33554432);         // (1024,512) bf16, 1 MB
  uint16_t* A2 = (uint16_t*)(ws + 34603008);         // (512,1024) bf16, 1 MB
  float*    Dd = (float*)   (ws + 35651584);         // (512) f32

  prep_mats<<<1024, 256, 0, stream>>>(Bbar, Cri, Dm, A1, A2, Dd);
  gemm1_fused<<<dim3(16, 8, BB), 256, 0, stream>>>(A1, u, Bu);
  scan_kernel<<<1024, 256, 0, stream>>>(Lam, Bu);
  gemm2_fused<<<dim3(16, 4, BB), 256, 0, stream>>>(A2, Bu, out, Dd, u);
}

// Round 3
// 193.020 us; speedup vs baseline: 1.0349x; 1.0349x over previous
//
#include <hip/hip_runtime.h>
#include <cstdint>
#include <cstddef>

// Problem dims
#define BB 8
#define HH 512
#define PP 512
#define LL 2048

typedef __attribute__((ext_vector_type(8))) __bf16 bf16x8;
typedef __attribute__((ext_vector_type(4))) float f32x4;

__device__ __forceinline__ uint16_t f2bf(float f) {
  uint32_t u = __builtin_bit_cast(uint32_t, f);
  u += 0x7FFFu + ((u >> 16) & 1u);   // RNE
  return (uint16_t)(u >> 16);
}

__device__ __forceinline__ void async_copy16(const void* gptr, void* ldsptr) {
  __builtin_amdgcn_global_load_lds(
      (const __attribute__((address_space(1))) unsigned int*)gptr,
      (__attribute__((address_space(3))) unsigned int*)ldsptr,
      16, 0, 0);
}

// ---------------------------------------------------------------------------
// prep: A1 (1024x512 bf16) = [B_re; B_im], A2 (512x1024 bf16) = [C_re, -C_im],
//       Dd (512 f32) = diag(D)
// ---------------------------------------------------------------------------
__global__ __launch_bounds__(256) void prep_mats(
    const float* __restrict__ Bbar, const float* __restrict__ Cri,
    const float* __restrict__ Dm,
    uint16_t* __restrict__ A1, uint16_t* __restrict__ A2,
    float* __restrict__ Dd) {
  int idx = blockIdx.x * 256 + threadIdx.x;   // 0 .. 512*512-1
  int p = idx >> 9, h = idx & 511;
  A1[(size_t)p * 512 + h]          = f2bf(Bbar[((size_t)p * 512 + h) * 2 + 0]);
  A1[(size_t)(512 + p) * 512 + h]  = f2bf(Bbar[((size_t)p * 512 + h) * 2 + 1]);
  int h2 = idx >> 9, p2 = idx & 511;
  A2[(size_t)h2 * 1024 + p2]        = f2bf( Cri[((size_t)h2 * 512 + p2) * 2 + 0]);
  A2[(size_t)h2 * 1024 + 512 + p2]  = f2bf(-Cri[((size_t)h2 * 512 + p2) * 2 + 1]);
  if (idx < 512) Dd[idx] = Dm[(size_t)idx * 512 + idx];
}

// ---------------------------------------------------------------------------
// scan: in-place on Bu (B, 1024, 2048) bf16 (rows p = re, rows 512+p = im)
// one wave per (b,p) chain; lane-local serial scan of 32 + Kogge-Stone combine
// ---------------------------------------------------------------------------
__global__ __launch_bounds__(256) void scan_kernel(
    const float* __restrict__ Lam, uint16_t* __restrict__ Bu) {
  const int gt = blockIdx.x * 256 + threadIdx.x;
  const int wave = gt >> 6, lane = gt & 63;
  const int b = wave >> 9, p = wave & 511;
  const float lr = Lam[p * 2 + 0], li = Lam[p * 2 + 1];
  float ar = lr, ai = li;
#pragma unroll
  for (int s = 0; s < 5; ++s) { float nr = ar * ar - ai * ai, ni = 2.f * ar * ai; ar = nr; ai = ni; }

  uint16_t* rowre = Bu + ((size_t)(b * 1024 + p)) * 2048 + lane * 32;
  uint16_t* rowim = Bu + ((size_t)(b * 1024 + 512 + p)) * 2048 + lane * 32;
  uint4 vr[4], vi[4];
#pragma unroll
  for (int q = 0; q < 4; ++q) { vr[q] = ((const uint4*)rowre)[q]; vi[q] = ((const uint4*)rowim)[q]; }

  float xr[32], xi[32];
  float sr = 0.f, si = 0.f;
#pragma unroll
  for (int q = 0; q < 4; ++q) {
    uint32_t wr[4] = {vr[q].x, vr[q].y, vr[q].z, vr[q].w};
    uint32_t wi[4] = {vi[q].x, vi[q].y, vi[q].z, vi[q].w};
#pragma unroll
    for (int d = 0; d < 4; ++d) {
      float br0 = __builtin_bit_cast(float, wr[d] << 16);
      float bi0 = __builtin_bit_cast(float, wi[d] << 16);
      float br1 = __builtin_bit_cast(float, wr[d] & 0xFFFF0000u);
      float bi1 = __builtin_bit_cast(float, wi[d] & 0xFFFF0000u);
      int j = q * 8 + d * 2;
      float nr = lr * sr - li * si + br0, ni = lr * si + li * sr + bi0;
      sr = nr; si = ni; xr[j] = sr; xi[j] = si;
      nr = lr * sr - li * si + br1; ni = lr * si + li * sr + bi1;
      sr = nr; si = ni; xr[j + 1] = sr; xi[j + 1] = si;
    }
  }
  float Ar = ar, Ai = ai, Sr = sr, Si = si;
#pragma unroll
  for (int off = 1; off < 64; off <<= 1) {
    float pAr = __shfl_up(Ar, off), pAi = __shfl_up(Ai, off);
    float pSr = __shfl_up(Sr, off), pSi = __shfl_up(Si, off);
    if (lane >= off) {
      float tSr = Ar * pSr - Ai * pSi + Sr;
      float tSi = Ar * pSi + Ai * pSr + Si;
      float tAr = Ar * pAr - Ai * pAi;
      float tAi = Ar * pAi + Ai * pAr;
      Sr = tSr; Si = tSi; Ar = tAr; Ai = tAi;
    }
  }
  float Cr = __shfl_up(Sr, 1), Ci = __shfl_up(Si, 1);
  if (lane == 0) { Cr = 0.f; Ci = 0.f; }
  float fr_ = lr * Cr - li * Ci, fi_ = lr * Ci + li * Cr;
#pragma unroll
  for (int j = 0; j < 32; ++j) {
    xr[j] += fr_; xi[j] += fi_;
    float nfr = fr_ * lr - fi_ * li, nfi = fr_ * li + fi_ * lr;
    fr_ = nfr; fi_ = nfi;
  }
#pragma unroll
  for (int q = 0; q < 4; ++q) {
    uint32_t wr[4], wi[4];
#pragma unroll
    for (int d = 0; d < 4; ++d) {
      int j = q * 8 + d * 2;
      wr[d] = (uint32_t)f2bf(xr[j]) | ((uint32_t)f2bf(xr[j + 1]) << 16);
      wi[d] = (uint32_t)f2bf(xi[j]) | ((uint32_t)f2bf(xi[j + 1]) << 16);
    }
    ((uint4*)rowre)[q] = make_uint4(wr[0], wr[1], wr[2], wr[3]);
    ((uint4*)rowim)[q] = make_uint4(wi[0], wi[1], wi[2], wi[3]);
  }
}

// ---------------------------------------------------------------------------
// GEMM1 fused+pipelined: Bu[b,m,l] = sum_h A1[m,h]*u[b,h,l]. M=1024,N=2048,K=512
// Double-buffered LDS; per iter: issue async A(k+1) + global->VGPR B(k+1),
// MFMA on resident tile k, convert/ds_write B(k+1), one barrier.
// ---------------------------------------------------------------------------
__global__ __launch_bounds__(256) void gemm1_fused(
    const uint16_t* __restrict__ A, const float* __restrict__ U,
    uint16_t* __restrict__ Bu) {
  __shared__ __align__(16) uint16_t Alds[2][128 * 32];
  __shared__ __align__(16) uint16_t Blds[2][128 * 40];
  const int t = threadIdx.x, lane = t & 63, w = t >> 6;
  const int m0 = blockIdx.y * 128, n0 = blockIdx.x * 128, b = blockIdx.z;

  const int ra = t >> 2;
  const int qa = ((t & 3) ^ ((ra >> 1) & 3)) * 8;   // source chunk swizzle
  const uint16_t* gA0 = A + (size_t)(m0 + ra) * 512 + qa;
  const uint16_t* gA1 = A + (size_t)(m0 + 64 + ra) * 512 + qa;

  const int kp = t >> 4, lg = t & 15;
  const float* gB = U + ((size_t)b * 512 + 2 * kp) * 2048 + n0 + lg * 8;
  const int bcol = ((kp >> 2) ^ (lg & 3)) * 8 + (kp & 3) * 2;   // elem col in Blds row

  f32x4 acc[4][4];
#pragma unroll
  for (int i = 0; i < 4; ++i)
#pragma unroll
    for (int j = 0; j < 4; ++j) acc[i][j] = (f32x4){0.f, 0.f, 0.f, 0.f};

  const int wm = (w >> 1) * 64, wn = (w & 1) * 64;
  const int fr = lane & 15, fq = lane >> 4;
  const int aswz = (fq ^ ((fr >> 1) & 3)) * 8;

  float4 pb0, pb1, pb2, pb3;
  // ---- prologue: tile 0 resident in buffer 0
  async_copy16(gA0, &Alds[0][t * 8]);
  async_copy16(gA1, &Alds[0][2048 + t * 8]);
  pb0 = *(const float4*)(gB);
  pb1 = *(const float4*)(gB + 4);
  pb2 = *(const float4*)(gB + 2048);
  pb3 = *(const float4*)(gB + 2052);
  {
    float r0[8] = {pb0.x, pb0.y, pb0.z, pb0.w, pb1.x, pb1.y, pb1.z, pb1.w};
    float r1[8] = {pb2.x, pb2.y, pb2.z, pb2.w, pb3.x, pb3.y, pb3.z, pb3.w};
#pragma unroll
    for (int j = 0; j < 8; ++j)
      *(uint32_t*)&Blds[0][(lg * 8 + j) * 40 + bcol] =
          (uint32_t)f2bf(r0[j]) | ((uint32_t)f2bf(r1[j]) << 16);
  }
  __syncthreads();

#pragma unroll 2
  for (int it = 0; it < 16; ++it) {
    const int cur = it & 1, nxt = cur ^ 1;
    const bool pre = (it < 15);
    if (pre) {
      const int kb = (it + 1) * 32;
      async_copy16(gA0 + kb, &Alds[nxt][t * 8]);
      async_copy16(gA1 + kb, &Alds[nxt][2048 + t * 8]);
      const float* s0 = gB + (size_t)kb * 2048;
      pb0 = *(const float4*)(s0);
      pb1 = *(const float4*)(s0 + 4);
      pb2 = *(const float4*)(s0 + 2048);
      pb3 = *(const float4*)(s0 + 2052);
    }
    bf16x8 af[4], bfr[4];
#pragma unroll
    for (int i = 0; i < 4; ++i)
      af[i] = *(const bf16x8*)&Alds[cur][(wm + i * 16 + fr) * 32 + aswz];
#pragma unroll
    for (int j = 0; j < 4; ++j) {
      int n = wn + j * 16 + fr;
      bfr[j] = *(const bf16x8*)&Blds[cur][n * 40 + ((fq ^ ((n >> 3) & 3)) * 8)];
    }
#pragma unroll
    for (int i = 0; i < 4; ++i)
#pragma unroll
      for (int j = 0; j < 4; ++j)
        acc[i][j] = __builtin_amdgcn_mfma_f32_16x16x32_bf16(af[i], bfr[j], acc[i][j], 0, 0, 0);
    if (pre) {
      float r0[8] = {pb0.x, pb0.y, pb0.z, pb0.w, pb1.x, pb1.y, pb1.z, pb1.w};
      float r1[8] = {pb2.x, pb2.y, pb2.z, pb2.w, pb3.x, pb3.y, pb3.z, pb3.w};
#pragma unroll
      for (int j = 0; j < 8; ++j)
        *(uint32_t*)&Blds[nxt][(lg * 8 + j) * 40 + bcol] =
            (uint32_t)f2bf(r0[j]) | ((uint32_t)f2bf(r1[j]) << 16);
      __syncthreads();
    }
  }

  uint16_t* O = Bu + ((size_t)b * 1024 + m0) * 2048 + n0;
#pragma unroll
  for (int i = 0; i < 4; ++i)
#pragma unroll
    for (int j = 0; j < 4; ++j)
#pragma unroll
      for (int r = 0; r < 4; ++r) {
        int mm = wm + i * 16 + fq * 4 + r;
        int nn = wn + j * 16 + fr;
        O[(size_t)mm * 2048 + nn] = f2bf(acc[i][j][r]);
      }
}

// ---------------------------------------------------------------------------
// GEMM2 fused+pipelined: out[b,h,l] = gelu(sum_k A2[h,k]*x[b,k,l] + Dd[h]*u[b,h,l])
// M=512, N=2048, K=1024; B-operand = scanned Bu (bf16, l-contiguous).
// ---------------------------------------------------------------------------
__global__ __launch_bounds__(256) void gemm2_fused(
    const uint16_t* __restrict__ A, const uint16_t* __restrict__ X,
    float* __restrict__ Out, const float* __restrict__ Dd,
    const float* __restrict__ Uu) {
  __shared__ __align__(16) uint16_t Alds[2][128 * 32];
  __shared__ __align__(16) uint16_t Blds[2][128 * 40];
  const int t = threadIdx.x, lane = t & 63, w = t >> 6;
  const int m0 = blockIdx.y * 128, n0 = blockIdx.x * 128, b = blockIdx.z;

  const int ra = t >> 2;
  const int qa = ((t & 3) ^ ((ra >> 1) & 3)) * 8;
  const uint16_t* gA0 = A + (size_t)(m0 + ra) * 1024 + qa;
  const uint16_t* gA1 = A + (size_t)(m0 + 64 + ra) * 1024 + qa;

  const int kp = t >> 4, lg = t & 15;
  const uint16_t* gB = X + ((size_t)b * 1024 + 2 * kp) * 2048 + n0 + lg * 8;
  const int bcol = ((kp >> 2) ^ (lg & 3)) * 8 + (kp & 3) * 2;

  f32x4 acc[4][4];
#pragma unroll
  for (int i = 0; i < 4; ++i)
#pragma unroll
    for (int j = 0; j < 4; ++j) acc[i][j] = (f32x4){0.f, 0.f, 0.f, 0.f};

  const int wm = (w >> 1) * 64, wn = (w & 1) * 64;
  const int fr = lane & 15, fq = lane >> 4;
  const int aswz = (fq ^ ((fr >> 1) & 3)) * 8;

  uint4 q0, q1;
  // ---- prologue
  async_copy16(gA0, &Alds[0][t * 8]);
  async_copy16(gA1, &Alds[0][2048 + t * 8]);
  q0 = *(const uint4*)(gB);
  q1 = *(const uint4*)(gB + 2048);
  {
    uint32_t u0[4] = {q0.x, q0.y, q0.z, q0.w};
    uint32_t u1[4] = {q1.x, q1.y, q1.z, q1.w};
#pragma unroll
    for (int d = 0; d < 4; ++d) {
      *(uint32_t*)&Blds[0][(lg * 8 + 2 * d + 0) * 40 + bcol] = (u0[d] & 0xFFFFu) | (u1[d] << 16);
      *(uint32_t*)&Blds[0][(lg * 8 + 2 * d + 1) * 40 + bcol] = (u0[d] >> 16) | (u1[d] & 0xFFFF0000u);
    }
  }
  __syncthreads();

#pragma unroll 2
  for (int it = 0; it < 32; ++it) {
    const int cur = it & 1, nxt = cur ^ 1;
    const bool pre = (it < 31);
    if (pre) {
      const int kb = (it + 1) * 32;
      async_copy16(gA0 + kb, &Alds[nxt][t * 8]);
      async_copy16(gA1 + kb, &Alds[nxt][2048 + t * 8]);
      const uint16_t* s0 = gB + (size_t)kb * 2048;
      q0 = *(const uint4*)(s0);
      q1 = *(const uint4*)(s0 + 2048);
    }
    bf16x8 af[4], bfr[4];
#pragma unroll
    for (int i = 0; i < 4; ++i)
      af[i] = *(const bf16x8*)&Alds[cur][(wm + i * 16 + fr) * 32 + aswz];
#pragma unroll
    for (int j = 0; j < 4; ++j) {
      int n = wn + j * 16 + fr;
      bfr[j] = *(const bf16x8*)&Blds[cur][n * 40 + ((fq ^ ((n >> 3) & 3)) * 8)];
    }
#pragma unroll
    for (int i = 0; i < 4; ++i)
#pragma unroll
      for (int j = 0; j < 4; ++j)
        acc[i][j] = __builtin_amdgcn_mfma_f32_16x16x32_bf16(af[i], bfr[j], acc[i][j], 0, 0, 0);
    if (pre) {
      uint32_t u0[4] = {q0.x, q0.y, q0.z, q0.w};
      uint32_t u1[4] = {q1.x, q1.y, q1.z, q1.w};
#pragma unroll
      for (int d = 0; d < 4; ++d) {
        *(uint32_t*)&Blds[nxt][(lg * 8 + 2 * d + 0) * 40 + bcol] = (u0[d] & 0xFFFFu) | (u1[d] << 16);
        *(uint32_t*)&Blds[nxt][(lg * 8 + 2 * d + 1) * 40 + bcol] = (u0[d] >> 16) | (u1[d] & 0xFFFF0000u);
      }
      __syncthreads();
    }
  }

  const size_t base = ((size_t)b * 512 + m0) * 2048 + n0;
  float* O = Out + base;
  const float* Ub = Uu + base;
#pragma unroll
  for (int i = 0; i < 4; ++i)
#pragma unroll
    for (int r = 0; r < 4; ++r) {
      int mm = wm + i * 16 + fq * 4 + r;
      float dv = Dd[m0 + mm];
#pragma unroll
      for (int j = 0; j < 4; ++j) {
        int nn = wn + j * 16 + fr;
        float xv = acc[i][j][r] + dv * Ub[(size_t)mm * 2048 + nn];
        O[(size_t)mm * 2048 + nn] = 0.5f * xv * (1.f + erff(xv * 0.70710678118654752f));
      }
    }
}

// ---------------------------------------------------------------------------
extern "C" void kernel_launch(void* const* d_in, const int* in_sizes, int n_in,
                              void* d_out, int out_size, void* d_ws, size_t ws_size,
                              hipStream_t stream) {
  const float* u    = (const float*)d_in[0];   // (8,512,2048)
  const float* Lam  = (const float*)d_in[1];   // (512,2)
  const float* Bbar = (const float*)d_in[2];   // (512,512,2)
  const float* Cri  = (const float*)d_in[3];   // (512,512,2)
  const float* Dm   = (const float*)d_in[4];   // (512,512)
  float* out = (float*)d_out;

  char* ws = (char*)d_ws;
  uint16_t* Bu = (uint16_t*)(ws);                    // (8,1024,2048) bf16, 33.55 MB
  uint16_t* A1 = (uint16_t*)(ws + 33554432);         // (1024,512) bf16, 1 MB
  uint16_t* A2 = (uint16_t*)(ws + 34603008);         // (512,1024) bf16, 1 MB
  float*    Dd = (float*)   (ws + 35651584);         // (512) f32

  prep_mats<<<1024, 256, 0, stream>>>(Bbar, Cri, Dm, A1, A2, Dd);
  gemm1_fused<<<dim3(16, 8, BB), 256, 0, stream>>>(A1, u, Bu);
  scan_kernel<<<1024, 256, 0, stream>>>(Lam, Bu);
  gemm2_fused<<<dim3(16, 4, BB), 256, 0, stream>>>(A2, Bu, out, Dd, u);
}